// Round 6
// baseline (160.085 us; speedup 1.0000x reference)
//
#include <hip/hip_runtime.h>
#include <hip/hip_bf16.h>

#define B_DIM 8192
#define D_DIM 256
#define GRID_GEMM 512
#define NT 16   // 32-col tiles per block (512 cols per block)

constexpr float INV_T = 14.285714285714286f;   // 1/0.07; also the logsumexp shift M

typedef __bf16 bf16x8 __attribute__((ext_vector_type(8)));
typedef float  f32x16 __attribute__((ext_vector_type(16)));

#define GLOBAL_U32(p) ((const __attribute__((address_space(1))) unsigned int*)(p))
#define LDS_U32(p)    ((__attribute__((address_space(3))) unsigned int*)(p))

// s_waitcnt imm (gfx9): vm[3:0]=bits3:0, exp=bits6:4, lgkm=bits11:8, vm[5:4]=bits15:14
// vmcnt(8), expcnt/lgkmcnt = no-wait:
#define WAITCNT_VM8 0x0F78

__device__ inline unsigned short f2bf(float f) {
    union { float f; unsigned u; } x; x.f = f;
    unsigned r = x.u + 0x7fffu + ((x.u >> 16) & 1u);  // RNE
    return (unsigned short)(r >> 16);
}

// ONE fused kernel: phase 1 = normalize (each block: 16 q rows + 16 t rows),
// grid-wide spin barrier (512 blocks == resident capacity: 2 blocks/CU by
// 64.5 KB LDS, VGPR capped by launch_bounds(256,2)), phase 2 = R5's
// software-pipelined A-in-registers GEMM (raw s_barrier + vmcnt(8), 4 LDS
// buffers, prefetch distance 2), phase 3 = ticket finalize by last block.
__global__ __launch_bounds__(256, 2) void fused_kernel(
    const float* __restrict__ h, const float* __restrict__ r,
    const float* __restrict__ t,
    unsigned short* __restrict__ qws, unsigned short* __restrict__ tws,
    float* __restrict__ rowsum, float* __restrict__ diagsum,
    int* __restrict__ ticket, int* __restrict__ arrive,
    float* __restrict__ out)
{
    __shared__ __align__(16) unsigned char ldsB[4][32 * 512];   // 64 KB
    __shared__ float wred[4];
    __shared__ int lastflag;

    const int tid  = threadIdx.x;
    const int lane = tid & 63;
    const int w    = tid >> 6;
    const int l31  = lane & 31;
    const int hi   = lane >> 5;

    // ================= phase 1: normalize 32 rows =================
    // waves 0,1: q rows (h+r); waves 2,3: t rows. 8 rows per wave.
#pragma unroll
    for (int j = 0; j < 8; ++j) {
        const int task = w * 8 + j;                 // 0..31
        const int row  = blockIdx.x * 16 + (task & 15);
        const bool isQ = task < 16;                 // wave-uniform
        float4 v;
        if (isQ) {
            float4 a = ((const float4*)h)[row * 64 + lane];
            float4 b = ((const float4*)r)[row * 64 + lane];
            v = make_float4(a.x + b.x, a.y + b.y, a.z + b.z, a.w + b.w);
        } else {
            v = ((const float4*)t)[row * 64 + lane];
        }
        float s = v.x * v.x + v.y * v.y + v.z * v.z + v.w * v.w;
#pragma unroll
        for (int off = 32; off; off >>= 1) s += __shfl_xor(s, off, 64);
        float scale = 1.0f / fmaxf(sqrtf(s), 1e-12f);
        ushort4 o;
        o.x = f2bf(v.x * scale);
        o.y = f2bf(v.y * scale);
        o.z = f2bf(v.z * scale);
        o.w = f2bf(v.w * scale);
        ((ushort4*)(isQ ? qws : tws))[row * 64 + lane] = o;
    }

    // ================= grid-wide spin barrier =================
    __syncthreads();
    if (tid == 0) {
        __threadfence();   // release phase-1 stores device-wide
        __hip_atomic_fetch_add(arrive, 1, __ATOMIC_ACQ_REL,
                               __HIP_MEMORY_SCOPE_AGENT);
        while (__hip_atomic_load(arrive, __ATOMIC_ACQUIRE,
                                 __HIP_MEMORY_SCOPE_AGENT) < GRID_GEMM)
            __builtin_amdgcn_s_sleep(1);
    }
    __syncthreads();

    // ================= phase 2: GEMM + exp-sum =================
    const int cc   = blockIdx.x & 15;        // col chunk (fast -> XCD locality)
    const int rb   = blockIdx.x >> 4;        // row block 0..31
    const int row0 = rb * 256 + w * 64;      // this wave's 64 rows
    const int col0 = cc * 512;

    // staging map: slot s -> row n = s>>5, phys chunk p = s&31,
    // logical chunk kc = p ^ (n&7); global ofs = n*512 + kc*16
    int srel[4];
#pragma unroll
    for (int it = 0; it < 4; ++it) {
        int s = it * 256 + tid;
        int n = s >> 5;
        int kc = (s & 31) ^ (n & 7);
        srel[it] = n * 512 + kc * 16;
    }

#define STAGE(snt, bufi)                                                     \
    {                                                                        \
        const unsigned char* gs = (const unsigned char*)tws +                \
                                  (size_t)(col0 + (snt) * 32) * 512;         \
        _Pragma("unroll")                                                    \
        for (int it = 0; it < 4; ++it)                                       \
            __builtin_amdgcn_global_load_lds(                                \
                GLOBAL_U32(gs + srel[it]),                                   \
                LDS_U32(&ldsB[bufi][(it * 256 + tid) * 16]), 16, 0, 0);      \
    }

    STAGE(0, 0);
    STAGE(1, 1);

    // A fragments in registers: rows row0..row0+63, full K=256
    // 32x32x16 A layout: m = lane&31, k = ks*16 + hi*8 + j (16B per frag)
    bf16x8 a[2][16];
    {
        const unsigned char* abase =
            (const unsigned char*)qws + (size_t)(row0 + l31) * 512 + hi * 16;
#pragma unroll
        for (int rt = 0; rt < 2; ++rt)
#pragma unroll
            for (int ks = 0; ks < 16; ++ks)
                a[rt][ks] = *(const bf16x8*)(abase + rt * (32 * 512) + ks * 32);
    }

    f32x16 rowacc[2] = {};
    float diagacc = 0.f;
    const int nsw = l31 & 7;

    for (int nt = 0; nt < NT; ++nt) {
        // prefetch distance 2; tail: dummy re-stage keeps in-flight uniform.
        const int snt = (nt + 2 < NT) ? nt + 2 : NT - 1;
        STAGE(snt, (nt + 2) & 3);

        // wait only for tile nt's loads (8 newer insts stay in flight)
        __builtin_amdgcn_s_waitcnt(WAITCNT_VM8);
        __builtin_amdgcn_s_barrier();

        const unsigned char* bbuf = ldsB[nt & 3];
        f32x16 acc0 = {}, acc1 = {};
#pragma unroll
        for (int ks = 0; ks < 16; ++ks) {
            int kc = ks * 2 + hi;
            bf16x8 b = *(const bf16x8*)(bbuf + l31 * 512 + ((kc ^ nsw) * 16));
            acc0 = __builtin_amdgcn_mfma_f32_32x32x16_bf16(a[0][ks], b, acc0, 0, 0, 0);
            acc1 = __builtin_amdgcn_mfma_f32_32x32x16_bf16(a[1][ks], b, acc1, 0, 0, 0);
        }

#pragma unroll
        for (int g = 0; g < 16; ++g) {
            rowacc[0][g] += __expf(fmaf(acc0[g], INV_T, -INV_T));
            rowacc[1][g] += __expf(fmaf(acc1[g], INV_T, -INV_T));
        }

        // diagonal tiles: wave-uniform, at most 2 of 16 iterations
        const int c0t = col0 + nt * 32;
        if (c0t == row0) {
#pragma unroll
            for (int g = 0; g < 16; ++g) {
                int rm = (g & 3) + 8 * (g >> 2) + 4 * hi;
                if (l31 == rm) diagacc += acc0[g] * INV_T;
            }
        }
        if (c0t == row0 + 32) {
#pragma unroll
            for (int g = 0; g < 16; ++g) {
                int rm = (g & 3) + 8 * (g >> 2) + 4 * hi;
                if (l31 == rm) diagacc += acc1[g] * INV_T;
            }
        }
    }

    // once per block: reduce across the 32 column-lanes, then atomics
#pragma unroll
    for (int rt = 0; rt < 2; ++rt)
#pragma unroll
        for (int g = 0; g < 16; ++g) {
            float s = rowacc[rt][g];
            s += __shfl_xor(s, 1, 64);
            s += __shfl_xor(s, 2, 64);
            s += __shfl_xor(s, 4, 64);
            s += __shfl_xor(s, 8, 64);
            s += __shfl_xor(s, 16, 64);
            if (l31 == 0) {
                int grow = row0 + rt * 32 + (g & 3) + 8 * (g >> 2) + 4 * hi;
                atomicAdd(&rowsum[grow], s);
            }
        }

    float dsum = diagacc;
#pragma unroll
    for (int off = 32; off; off >>= 1) dsum += __shfl_xor(dsum, off, 64);
    if (lane == 0 && dsum != 0.f) atomicAdd(diagsum, dsum);

    // ================= phase 3: ticket finalize =================
    __syncthreads();
    if (tid == 0) {
        __threadfence();
        int old = __hip_atomic_fetch_add(ticket, 1, __ATOMIC_ACQ_REL,
                                         __HIP_MEMORY_SCOPE_AGENT);
        lastflag = (old == GRID_GEMM - 1);
    }
    __syncthreads();
    if (!lastflag) return;

    float lsum = 0.f;
    for (int rr = tid; rr < B_DIM; rr += 256) {
        float rs = __hip_atomic_load(&rowsum[rr], __ATOMIC_RELAXED,
                                     __HIP_MEMORY_SCOPE_AGENT);
        lsum += __logf(rs);
    }
#pragma unroll
    for (int off = 32; off; off >>= 1) lsum += __shfl_xor(lsum, off, 64);
    if (lane == 0) wred[w] = lsum;
    __syncthreads();
    if (tid == 0) {
        float ds = __hip_atomic_load(diagsum, __ATOMIC_RELAXED,
                                     __HIP_MEMORY_SCOPE_AGENT);
        float total = wred[0] + wred[1] + wred[2] + wred[3]
                    + (float)B_DIM * INV_T   // + M per row
                    - ds;                    // - positive logits
        out[0] = total / (float)B_DIM;
    }
}

extern "C" void kernel_launch(void* const* d_in, const int* in_sizes, int n_in,
                              void* d_out, int out_size, void* d_ws, size_t ws_size,
                              hipStream_t stream)
{
    const float* h = (const float*)d_in[0];
    const float* r = (const float*)d_in[1];
    const float* t = (const float*)d_in[2];

    unsigned char* ws = (unsigned char*)d_ws;
    unsigned short* qws = (unsigned short*)ws;                        // 4 MB
    unsigned short* tws = (unsigned short*)(ws + 4u * 1024 * 1024);   // 4 MB
    float* rowsum  = (float*)(ws + 8u * 1024 * 1024);                 // 32 KB
    float* diagsum = (float*)(ws + 8u * 1024 * 1024 + 32768u);
    int*   ticket  = (int*)  (ws + 8u * 1024 * 1024 + 32768u + 4);
    int*   arrive  = (int*)  (ws + 8u * 1024 * 1024 + 32768u + 8);

    // zero rowsum + control block (diagsum/ticket/arrive) in one shot
    hipMemsetAsync(ws + 8u * 1024 * 1024, 0, 32768u + 16, stream);

    fused_kernel<<<GRID_GEMM, 256, 0, stream>>>(
        h, r, t, qws, tws, rowsum, diagsum, ticket, arrive, (float*)d_out);
}

// Round 7
// 149.106 us; speedup vs baseline: 1.0736x; 1.0736x over previous
//
#include <hip/hip_runtime.h>
#include <hip/hip_bf16.h>

#define B_DIM 8192
#define D_DIM 256
#define GRID_GEMM 512
#define NT 16   // 32-col panels per block (512 cols per block)

constexpr float INV_T = 14.285714285714286f;   // 1/0.07; also the logsumexp shift M

typedef __bf16 bf16x8 __attribute__((ext_vector_type(8)));
typedef float  f32x16 __attribute__((ext_vector_type(16)));

__device__ inline unsigned short f2bf(float f) {
    union { float f; unsigned u; } x; x.f = f;
    unsigned r = x.u + 0x7fffu + ((x.u >> 16) & 1u);  // RNE
    return (unsigned short)(r >> 16);
}

// Kernel 1: q = normalize(h+r), t = normalize(t) -> bf16 workspace in
// PRE-SWIZZLED fragment layout: buf[panel = row>>5][chunk c = byte16][n = row&31],
// i.e. byte addr = (row>>5)*16384 + c*512 + (row&31)*16. With this layout every
// MFMA fragment load in the GEMM (chunk c fixed per wave, n = lane) is a
// contiguous 1 KB wave load. Two rows per wave for ILP (the 6-shuffle
// reduction chain was the latency limiter at 1 row/wave).
__global__ __launch_bounds__(256) void norm_kernel(
    const float* __restrict__ h, const float* __restrict__ r,
    const float* __restrict__ t,
    unsigned short* __restrict__ qws, unsigned short* __restrict__ tws)
{
    const int lane = threadIdx.x & 63;
    const int w    = threadIdx.x >> 6;
    const int task0 = blockIdx.x * 8 + w * 2;      // 2 consecutive tasks per wave
    const bool isQ  = task0 < B_DIM;               // wave-uniform (boundary at block 1024)
    const int row0  = isQ ? task0 : task0 - B_DIM;

    float4 v[2];
#pragma unroll
    for (int j = 0; j < 2; ++j) {
        const int row = row0 + j;
        if (isQ) {
            float4 a = ((const float4*)h)[row * 64 + lane];
            float4 b = ((const float4*)r)[row * 64 + lane];
            v[j] = make_float4(a.x + b.x, a.y + b.y, a.z + b.z, a.w + b.w);
        } else {
            v[j] = ((const float4*)t)[row * 64 + lane];
        }
    }
    float s[2];
#pragma unroll
    for (int j = 0; j < 2; ++j)
        s[j] = v[j].x * v[j].x + v[j].y * v[j].y + v[j].z * v[j].z + v[j].w * v[j].w;
    // interleaved butterflies: two independent chains in flight
#pragma unroll
    for (int off = 32; off; off >>= 1) {
        s[0] += __shfl_xor(s[0], off, 64);
        s[1] += __shfl_xor(s[1], off, 64);
    }
    ushort4* dst = (ushort4*)(isQ ? qws : tws);
#pragma unroll
    for (int j = 0; j < 2; ++j) {
        const int row = row0 + j;
        float scale = 1.0f / fmaxf(sqrtf(s[j]), 1e-12f);
        ushort4 o;
        o.x = f2bf(v[j].x * scale);
        o.y = f2bf(v[j].y * scale);
        o.z = f2bf(v[j].z * scale);
        o.w = f2bf(v[j].w * scale);
        // lane l holds elements [l*4, l*4+4) = 8 bytes = half of 16B chunk c=l>>1
        // ushort4-unit offset: panel*2048 + (l>>1)*64 + (row&31)*2 + (l&1)
        dst[(row >> 5) * 2048 + (lane >> 1) * 64 + (row & 31) * 2 + (lane & 1)] = o;
    }
}

// Kernel 2: LDS-free, barrier-free streaming GEMM + fused exp-sum/diag +
// ticket finalize. Grid 512 = 32 row-blocks x 16 col-chunks (cc fast -> each
// XCD's B slice = 2 chunks = 512 KB, L2-resident). Wave = 64 rows x 32 cols
// (mfma_f32_32x32x16_bf16, A in 128 VGPRs loaded once). B fragments loaded
// directly global->VGPR as contiguous 1KB wave loads from the swizzled
// layout; no __syncthreads in the k-loop, waves free-run, compiler pipelines
// with fine-grained vmcnt.
__global__ __launch_bounds__(256) void gemm_lse_kernel(
    const unsigned char* __restrict__ qws, const unsigned char* __restrict__ tws,
    float* __restrict__ rowsum, float* __restrict__ diagsum,
    int* __restrict__ ticket, float* __restrict__ out)
{
    __shared__ float wred[4];
    __shared__ int lastflag;

    const int tid  = threadIdx.x;
    const int lane = tid & 63;
    const int w    = tid >> 6;
    const int l31  = lane & 31;
    const int hi   = lane >> 5;

    const int cc   = blockIdx.x & 15;        // col chunk (fast -> XCD locality)
    const int rb   = blockIdx.x >> 4;        // row block 0..31
    const int row0 = rb * 256 + w * 64;      // this wave's 64 rows
    const int col0 = cc * 512;

    // A fragments: a[rt][ks] = qws[panel(row0+rt*32)][chunk ks*2+hi][l31]
    // bf16x8-unit offset: panel*1024 + (ks*2+hi)*32 + l31
    bf16x8 a[2][16];
    {
        const bf16x8* qa = (const bf16x8*)qws;
#pragma unroll
        for (int rt = 0; rt < 2; ++rt) {
            const int pofs = ((row0 + rt * 32) >> 5) * 1024 + hi * 32 + l31;
#pragma unroll
            for (int ks = 0; ks < 16; ++ks)
                a[rt][ks] = qa[pofs + ks * 64];
        }
    }

    f32x16 rowacc[2] = {};
    float diagacc = 0.f;
    const bf16x8* tb = (const bf16x8*)tws;

    for (int nt = 0; nt < NT; ++nt) {
        const int bofs = ((col0 >> 5) + nt) * 1024 + hi * 32 + l31;
        f32x16 acc0 = {}, acc1 = {};
#pragma unroll
        for (int ks = 0; ks < 16; ++ks) {
            bf16x8 b = tb[bofs + ks * 64];   // contiguous 1KB wave load
            acc0 = __builtin_amdgcn_mfma_f32_32x32x16_bf16(a[0][ks], b, acc0, 0, 0, 0);
            acc1 = __builtin_amdgcn_mfma_f32_32x32x16_bf16(a[1][ks], b, acc1, 0, 0, 0);
        }

#pragma unroll
        for (int g = 0; g < 16; ++g) {
            rowacc[0][g] += __expf(fmaf(acc0[g], INV_T, -INV_T));
            rowacc[1][g] += __expf(fmaf(acc1[g], INV_T, -INV_T));
        }

        // diagonal tiles: wave-uniform, at most 2 of 16 iterations
        const int c0t = col0 + nt * 32;
        if (c0t == row0) {
#pragma unroll
            for (int g = 0; g < 16; ++g) {
                int rm = (g & 3) + 8 * (g >> 2) + 4 * hi;
                if (l31 == rm) diagacc += acc0[g] * INV_T;
            }
        }
        if (c0t == row0 + 32) {
#pragma unroll
            for (int g = 0; g < 16; ++g) {
                int rm = (g & 3) + 8 * (g >> 2) + 4 * hi;
                if (l31 == rm) diagacc += acc1[g] * INV_T;
            }
        }
    }

    // once per block: reduce across the 32 column-lanes, then atomics
#pragma unroll
    for (int rt = 0; rt < 2; ++rt)
#pragma unroll
        for (int g = 0; g < 16; ++g) {
            float s = rowacc[rt][g];
            s += __shfl_xor(s, 1, 64);
            s += __shfl_xor(s, 2, 64);
            s += __shfl_xor(s, 4, 64);
            s += __shfl_xor(s, 8, 64);
            s += __shfl_xor(s, 16, 64);
            if (l31 == 0) {
                int grow = row0 + rt * 32 + (g & 3) + 8 * (g >> 2) + 4 * hi;
                atomicAdd(&rowsum[grow], s);
            }
        }

    float dsum = diagacc;
#pragma unroll
    for (int off = 32; off; off >>= 1) dsum += __shfl_xor(dsum, off, 64);
    if (lane == 0 && dsum != 0.f) atomicAdd(diagsum, dsum);

    // ticket: last block computes the loss
    __syncthreads();
    if (tid == 0) {
        __threadfence();
        int old = __hip_atomic_fetch_add(ticket, 1, __ATOMIC_ACQ_REL,
                                         __HIP_MEMORY_SCOPE_AGENT);
        lastflag = (old == GRID_GEMM - 1);
    }
    __syncthreads();
    if (!lastflag) return;

    float lsum = 0.f;
    for (int rr = tid; rr < B_DIM; rr += 256) {
        float rs = __hip_atomic_load(&rowsum[rr], __ATOMIC_RELAXED,
                                     __HIP_MEMORY_SCOPE_AGENT);
        lsum += __logf(rs);
    }
#pragma unroll
    for (int off = 32; off; off >>= 1) lsum += __shfl_xor(lsum, off, 64);
    if (lane == 0) wred[w] = lsum;
    __syncthreads();
    if (tid == 0) {
        float ds = __hip_atomic_load(diagsum, __ATOMIC_RELAXED,
                                     __HIP_MEMORY_SCOPE_AGENT);
        float total = wred[0] + wred[1] + wred[2] + wred[3]
                    + (float)B_DIM * INV_T   // + M per row
                    - ds;                    // - positive logits
        out[0] = total / (float)B_DIM;
    }
}

extern "C" void kernel_launch(void* const* d_in, const int* in_sizes, int n_in,
                              void* d_out, int out_size, void* d_ws, size_t ws_size,
                              hipStream_t stream)
{
    const float* h = (const float*)d_in[0];
    const float* r = (const float*)d_in[1];
    const float* t = (const float*)d_in[2];

    unsigned char* ws = (unsigned char*)d_ws;
    unsigned short* qws = (unsigned short*)ws;                        // 4 MB
    unsigned short* tws = (unsigned short*)(ws + 4u * 1024 * 1024);   // 4 MB
    float* rowsum  = (float*)(ws + 8u * 1024 * 1024);                 // 32 KB
    float* diagsum = (float*)(ws + 8u * 1024 * 1024 + 32768u);
    int*   ticket  = (int*)  (ws + 8u * 1024 * 1024 + 32768u + 4);

    // zero rowsum + diagsum + ticket
    hipMemsetAsync(ws + 8u * 1024 * 1024, 0, 32768u + 16, stream);

    norm_kernel<<<2048, 256, 0, stream>>>(h, r, t, qws, tws);
    gemm_lse_kernel<<<GRID_GEMM, 256, 0, stream>>>(
        (const unsigned char*)qws, (const unsigned char*)tws,
        rowsum, diagsum, ticket, (float*)d_out);
}